// Round 3
// baseline (392.775 us; speedup 1.0000x reference)
//
#include <hip/hip_runtime.h>
#include <math.h>

#define N_TOK 32768
#define DIM   128
#define KCODES 1024
#define SPLITS 4
#define CPS   256   // codes per split

// ---- workspace layout (bytes) ----
// keys:   u64[32768]  @ 0        (262144)  packed (score_bits<<32)|code, atomicMin-merged
// esq:    float[1024] @ 262144   (4096)
// counts: int[1024]   @ 266240   (4096)
// lacc:   double[64]  @ 270336   (512)

// One fused prep launch: init keys/counts/lacc + esq (numpy pairwise ||e||^2).
__global__ __launch_bounds__(256) void vq_prep(const float* __restrict__ emb,
                                               float* __restrict__ esq,
                                               unsigned long long* __restrict__ keys,
                                               int* __restrict__ counts,
                                               double* __restrict__ lacc) {
    const int t = blockIdx.x * 256 + threadIdx.x;   // grid 128*256 = 32768
    keys[t] = 0xFFFFFFFFFFFFFFFFull;
    if (t < KCODES) counts[t] = 0;
    if (t < 64) lacc[t] = 0.0;
    if (t < KCODES * 8) {
        // numpy pairwise_sum replica: 8 partials stride 8, combine tree. (verified R1/R2)
        const int lane8 = t & 7, row = t >> 3;
        const float* p = emb + ((size_t)row << 7) + lane8;
        float r = __fmul_rn(p[0], p[0]);
#pragma unroll
        for (int m = 1; m < 16; ++m) {
            const float v = p[8 * m];
            r = __fadd_rn(r, __fmul_rn(v, v));
        }
        float s = __fadd_rn(r, __shfl_xor(r, 1));
        s = __fadd_rn(s, __shfl_xor(s, 2));
        s = __fadd_rn(s, __shfl_xor(s, 4));
        if (lane8 == 0) esq[row] = s;
    }
}

// lane = token; z row resident in VGPRs (unconditional init -> no demotion).
// e rows are wave-uniform -> s_load into SGPRs, fmaf(s, v, v). No LDS at all.
// score = fp32((A + B) - 2*dot), dot = sequential-d fmaf chain (exact, as R1/R2).
__global__ __launch_bounds__(256, 3) void vq_argmin(
    const float* __restrict__ z, const float* __restrict__ emb,
    const float* __restrict__ esq, unsigned long long* __restrict__ keys)
{
    const int tid = threadIdx.x;
    const int bt = blockIdx.x >> 2;        // token group (0..127)
    const int sp = blockIdx.x & 3;         // code split (0..3)
    const int token = bt * 256 + tid;
    const int code0 = sp * CPS;

    // ---- z row straight into registers (L1/L2 absorb the 4x line overfetch) ----
    float4 zr[32];
    const float4* zrow = (const float4*)(z + ((size_t)token << 7));
#pragma unroll
    for (int i = 0; i < 32; ++i) zr[i] = zrow[i];

    // ---- A = ||z||^2, exact numpy pairwise tree (8 partials stride 8) ----
    float4 r03, r47;
    r03.x = __fmul_rn(zr[0].x, zr[0].x); r03.y = __fmul_rn(zr[0].y, zr[0].y);
    r03.z = __fmul_rn(zr[0].z, zr[0].z); r03.w = __fmul_rn(zr[0].w, zr[0].w);
    r47.x = __fmul_rn(zr[1].x, zr[1].x); r47.y = __fmul_rn(zr[1].y, zr[1].y);
    r47.z = __fmul_rn(zr[1].z, zr[1].z); r47.w = __fmul_rn(zr[1].w, zr[1].w);
#pragma unroll
    for (int m = 1; m < 16; ++m) {
        const float4 p = zr[2 * m], q = zr[2 * m + 1];
        r03.x = __fadd_rn(r03.x, __fmul_rn(p.x, p.x));
        r03.y = __fadd_rn(r03.y, __fmul_rn(p.y, p.y));
        r03.z = __fadd_rn(r03.z, __fmul_rn(p.z, p.z));
        r03.w = __fadd_rn(r03.w, __fmul_rn(p.w, p.w));
        r47.x = __fadd_rn(r47.x, __fmul_rn(q.x, q.x));
        r47.y = __fadd_rn(r47.y, __fmul_rn(q.y, q.y));
        r47.z = __fadd_rn(r47.z, __fmul_rn(q.z, q.z));
        r47.w = __fadd_rn(r47.w, __fmul_rn(q.w, q.w));
    }
    const float A = __fadd_rn(
        __fadd_rn(__fadd_rn(r03.x, r03.y), __fadd_rn(r03.z, r03.w)),
        __fadd_rn(__fadd_rn(r47.x, r47.y), __fadd_rn(r47.z, r47.w)));

    float best = 3.402823466e+38f;
    unsigned bidx = 0;

    // ---- 4 codes at a time: 4 indep fmaf chains, e via wave-uniform s_load ----
#pragma unroll 2
    for (int cg = 0; cg < CPS; cg += 4) {
        const int code = __builtin_amdgcn_readfirstlane(code0 + cg);  // pin uniform
        const float* ep = emb + ((size_t)code << 7);
        const float4* e0 = (const float4*)ep;
        const float4* e1 = (const float4*)(ep + DIM);
        const float4* e2 = (const float4*)(ep + 2 * DIM);
        const float4* e3 = (const float4*)(ep + 3 * DIM);
        float a0 = 0.f, a1 = 0.f, a2 = 0.f, a3 = 0.f;
#pragma unroll
        for (int i = 0; i < 32; ++i) {
            const float4 x0 = e0[i], x1 = e1[i], x2 = e2[i], x3 = e3[i];
            const float4 zz = zr[i];
            a0 = fmaf(x0.x, zz.x, a0); a1 = fmaf(x1.x, zz.x, a1);
            a2 = fmaf(x2.x, zz.x, a2); a3 = fmaf(x3.x, zz.x, a3);
            a0 = fmaf(x0.y, zz.y, a0); a1 = fmaf(x1.y, zz.y, a1);
            a2 = fmaf(x2.y, zz.y, a2); a3 = fmaf(x3.y, zz.y, a3);
            a0 = fmaf(x0.z, zz.z, a0); a1 = fmaf(x1.z, zz.z, a1);
            a2 = fmaf(x2.z, zz.z, a2); a3 = fmaf(x3.z, zz.z, a3);
            a0 = fmaf(x0.w, zz.w, a0); a1 = fmaf(x1.w, zz.w, a1);
            a2 = fmaf(x2.w, zz.w, a2); a3 = fmaf(x3.w, zz.w, a3);
        }
        const float b0 = esq[code + 0], b1 = esq[code + 1];
        const float b2 = esq[code + 2], b3 = esq[code + 3];
        const float s0 = __fsub_rn(__fadd_rn(A, b0), __fmul_rn(2.0f, a0));
        const float s1 = __fsub_rn(__fadd_rn(A, b1), __fmul_rn(2.0f, a1));
        const float s2 = __fsub_rn(__fadd_rn(A, b2), __fmul_rn(2.0f, a2));
        const float s3 = __fsub_rn(__fadd_rn(A, b3), __fmul_rn(2.0f, a3));
        if (s0 < best) { best = s0; bidx = code + 0; }   // ascending order keeps
        if (s1 < best) { best = s1; bidx = code + 1; }   // numpy first-index ties
        if (s2 < best) { best = s2; bidx = code + 2; }
        if (s3 < best) { best = s3; bidx = code + 3; }
    }

    // positive scores -> float bits order-preserving; low 32 = code (min code wins ties)
    const unsigned long long key =
        ((unsigned long long)__float_as_uint(best) << 32) | (unsigned long long)bidx;
    atomicMin(&keys[token], key);
}

// gather z_q, quantized = z + (z_q - z) exact; loss partials to 64 slots; counts.
__global__ __launch_bounds__(256) void vq_out(
    const float* __restrict__ z, const float* __restrict__ emb,
    const unsigned long long* __restrict__ keys, float* __restrict__ outq,
    double* __restrict__ lacc, int* __restrict__ counts)
{
    double ls = 0.0;
    for (int g = blockIdx.x * 256 + threadIdx.x; g < N_TOK * 32; g += 512 * 256) {
        const int t = g >> 5, dd = g & 31;
        const unsigned code = (unsigned)(keys[t] & 0xFFFFFFFFull);
        const float4 e4 = *(const float4*)(emb + ((size_t)code << 7) + (dd << 2));
        const float4 z4 = *(const float4*)(z + ((size_t)g << 2));

        const float dx = __fsub_rn(e4.x, z4.x);
        const float dy = __fsub_rn(e4.y, z4.y);
        const float dz = __fsub_rn(e4.z, z4.z);
        const float dw = __fsub_rn(e4.w, z4.w);

        float4 q;
        q.x = __fadd_rn(z4.x, dx);
        q.y = __fadd_rn(z4.y, dy);
        q.z = __fadd_rn(z4.z, dz);
        q.w = __fadd_rn(z4.w, dw);
        *(float4*)(outq + ((size_t)g << 2)) = q;

        ls += (double)__fmul_rn(dx, dx) + (double)__fmul_rn(dy, dy)
            + (double)__fmul_rn(dz, dz) + (double)__fmul_rn(dw, dw);
        if (dd == 0) atomicAdd(&counts[code], 1);
    }
#pragma unroll
    for (int off = 32; off > 0; off >>= 1) ls += __shfl_down(ls, off);
    __shared__ double wsum[4];
    if ((threadIdx.x & 63) == 0) wsum[threadIdx.x >> 6] = ls;
    __syncthreads();
    if (threadIdx.x == 0)
        atomicAdd(&lacc[blockIdx.x & 63], wsum[0] + wsum[1] + wsum[2] + wsum[3]);
}

__global__ __launch_bounds__(256) void vq_final(
    const int* __restrict__ counts, const double* __restrict__ lacc,
    float* __restrict__ outs)
{
    double h = 0.0;
    for (int k = threadIdx.x; k < KCODES; k += 256) {
        const double p = (double)counts[k] * (1.0 / (double)N_TOK);
        h += p * log(p + 1e-10);
    }
#pragma unroll
    for (int off = 32; off > 0; off >>= 1) h += __shfl_down(h, off);
    __shared__ double ws2[4];
    if ((threadIdx.x & 63) == 0) ws2[threadIdx.x >> 6] = h;
    __syncthreads();
    if (threadIdx.x == 0) {
        double L = 0.0;
        for (int i = 0; i < 64; ++i) L += lacc[i];
        outs[0] = (float)(1.25 * L / (double)((size_t)N_TOK * DIM));
        outs[1] = (float)exp(-(ws2[0] + ws2[1] + ws2[2] + ws2[3]));
    }
}

extern "C" void kernel_launch(void* const* d_in, const int* in_sizes, int n_in,
                              void* d_out, int out_size, void* d_ws, size_t ws_size,
                              hipStream_t stream) {
    const float* z   = (const float*)d_in[0];
    const float* emb = (const float*)d_in[1];

    float* outq = (float*)d_out;
    float* outs = outq + (size_t)N_TOK * DIM;

    char* ws = (char*)d_ws;
    unsigned long long* keys = (unsigned long long*)(ws);
    float*  esq    = (float*)(ws + 262144);
    int*    counts = (int*)(ws + 266240);
    double* lacc   = (double*)(ws + 270336);

    vq_prep<<<dim3(N_TOK / 256), dim3(256), 0, stream>>>(emb, esq, keys, counts, lacc);
    vq_argmin<<<dim3(SPLITS * (N_TOK / 256)), dim3(256), 0, stream>>>(z, emb, esq, keys);
    vq_out<<<dim3(512), dim3(256), 0, stream>>>(z, emb, keys, outq, lacc, counts);
    vq_final<<<dim3(1), dim3(256), 0, stream>>>(counts, lacc, outs);
}

// Round 5
// 275.268 us; speedup vs baseline: 1.4269x; 1.4269x over previous
//
#include <hip/hip_runtime.h>
#include <math.h>

#define N_TOK 32768
#define DIM   128
#define KCODES 1024
#define SPLITS 8
#define CPS   128   // codes per split

typedef __attribute__((ext_vector_type(8))) float f32x8;
typedef __attribute__((ext_vector_type(4))) float f32x4s;

// ---- workspace layout (bytes) ----
// keys:   u64[32768]  @ 0        (262144)  packed (score_bits<<32)|code, atomicMin-merged
// esq:    float[1024] @ 262144   (4096)
// counts: int[1024]   @ 266240   (4096)
// lacc:   double[64]  @ 270336   (512)

// One fused prep launch: init keys/counts/lacc + esq (numpy pairwise ||e||^2).
__global__ __launch_bounds__(256) void vq_prep(const float* __restrict__ emb,
                                               float* __restrict__ esq,
                                               unsigned long long* __restrict__ keys,
                                               int* __restrict__ counts,
                                               double* __restrict__ lacc) {
    const int t = blockIdx.x * 256 + threadIdx.x;   // grid 128*256 = 32768
    keys[t] = 0xFFFFFFFFFFFFFFFFull;
    if (t < KCODES) counts[t] = 0;
    if (t < 64) lacc[t] = 0.0;
    if (t < KCODES * 8) {
        const int lane8 = t & 7, row = t >> 3;
        const float* p = emb + ((size_t)row << 7) + lane8;
        float r = __fmul_rn(p[0], p[0]);
#pragma unroll
        for (int m = 1; m < 16; ++m) {
            const float v = p[8 * m];
            r = __fadd_rn(r, __fmul_rn(v, v));
        }
        float s = __fadd_rn(r, __shfl_xor(r, 1));
        s = __fadd_rn(s, __shfl_xor(s, 2));
        s = __fadd_rn(s, __shfl_xor(s, 4));
        if (lane8 == 0) esq[row] = s;
    }
}

// 4 codes' dims [k*8, k*8+8) -> one asm block of 4 s_load_dwordx8 (wave-level,
// SMEM path, zero VALU / zero LDS). Early-clobber so outputs can't alias base.
#define SLOADS(B, OFF)                                                      \
    asm volatile("s_load_dwordx8 %0, %4, %5\n\t"                            \
                 "s_load_dwordx8 %1, %4, %6\n\t"                            \
                 "s_load_dwordx8 %2, %4, %7\n\t"                            \
                 "s_load_dwordx8 %3, %4, %8"                                \
                 : "=&s"(B##0), "=&s"(B##1), "=&s"(B##2), "=&s"(B##3)       \
                 : "s"(ebase), "n"(OFF), "n"(OFF + 512), "n"(OFF + 1024),   \
                   "n"(OFF + 1536));

// SMEM completes out-of-order: lgkmcnt(0) is the only safe wait. "+s" binds the
// buffers so consumes can't be scheduled before the wait.
#define SWAITB(B)                                                           \
    asm volatile("s_waitcnt lgkmcnt(0)"                                     \
                 : "+s"(B##0), "+s"(B##1), "+s"(B##2), "+s"(B##3));

// 8 dims x 4 codes; e operands are SGPRs -> v_fma_f32 v,s,v,v (free broadcast).
// Sequential-d fmaf chain per code = exact same rounding as R1/R2 (verified).
#define CONSUME(B, K)                                                       \
    _Pragma("unroll")                                                       \
    for (int j = 0; j < 8; ++j) {                                           \
        const float zz = zf[(K) * 8 + j];                                   \
        a0 = fmaf(B##0[j], zz, a0);                                         \
        a1 = fmaf(B##1[j], zz, a1);                                         \
        a2 = fmaf(B##2[j], zz, a2);                                         \
        a3 = fmaf(B##3[j], zz, a3);                                         \
    }

#define STEP(BL, OFF, BC, K) SLOADS(BL, OFF) CONSUME(BC, K) SWAITB(BL)

__global__ __launch_bounds__(256, 3) void vq_argmin(
    const float* __restrict__ z, const float* __restrict__ emb,
    const float* __restrict__ esq, unsigned long long* __restrict__ keys)
{
    const int tid = threadIdx.x;
    const int bt = blockIdx.x >> 3;        // token group (0..127)
    const int sp = blockIdx.x & 7;         // code split (0..7)
    const int token = bt * 256 + tid;
    const int code0 = sp * CPS;

    // ---- z row -> VGPRs (only vector stream in the kernel) ----
    float zf[DIM];
    {
        const float4* zrow = (const float4*)(z + ((size_t)token << 7));
#pragma unroll
        for (int i = 0; i < 32; ++i) {
            const float4 v = zrow[i];
            zf[4 * i] = v.x; zf[4 * i + 1] = v.y;
            zf[4 * i + 2] = v.z; zf[4 * i + 3] = v.w;
        }
    }

    // ---- A = ||z||^2, exact numpy pairwise tree (8 partials stride 8) ----
    float r[8];
#pragma unroll
    for (int j = 0; j < 8; ++j) r[j] = __fmul_rn(zf[j], zf[j]);
#pragma unroll
    for (int m = 1; m < 16; ++m)
#pragma unroll
        for (int j = 0; j < 8; ++j)
            r[j] = __fadd_rn(r[j], __fmul_rn(zf[8 * m + j], zf[8 * m + j]));
    const float A = __fadd_rn(
        __fadd_rn(__fadd_rn(r[0], r[1]), __fadd_rn(r[2], r[3])),
        __fadd_rn(__fadd_rn(r[4], r[5]), __fadd_rn(r[6], r[7])));

    float best = 3.402823466e+38f;
    unsigned bidx = 0;

    const float* ebase = emb + ((size_t)code0 << 7);
    const float* esqp  = esq + code0;

#pragma clang loop unroll(disable)
    for (int cg = 0; cg < CPS; cg += 4) {
        f32x8 p0, p1, p2, p3, q0, q1, q2, q3;
        f32x4s eb;
        float a0 = 0.f, a1 = 0.f, a2 = 0.f, a3 = 0.f;
        asm volatile("s_load_dwordx4 %0, %1, 0"
                     : "=&s"(eb) : "s"(esqp));
        SLOADS(p, 0)
        SWAITB(p)
        STEP(q,  32, p,  0)
        STEP(p,  64, q,  1)
        STEP(q,  96, p,  2)
        STEP(p, 128, q,  3)
        STEP(q, 160, p,  4)
        STEP(p, 192, q,  5)
        STEP(q, 224, p,  6)
        STEP(p, 256, q,  7)
        STEP(q, 288, p,  8)
        STEP(p, 320, q,  9)
        STEP(q, 352, p, 10)
        STEP(p, 384, q, 11)
        STEP(q, 416, p, 12)
        STEP(p, 448, q, 13)
        STEP(q, 480, p, 14)
        CONSUME(q, 15)
        asm volatile("s_waitcnt lgkmcnt(0)" : "+s"(eb));  // free: already drained

        // combine exactly as numpy: fp32((A + B) - 2*dot)
        const int cb = code0 + cg;
        const float s0 = __fsub_rn(__fadd_rn(A, eb[0]), __fmul_rn(2.0f, a0));
        const float s1 = __fsub_rn(__fadd_rn(A, eb[1]), __fmul_rn(2.0f, a1));
        const float s2 = __fsub_rn(__fadd_rn(A, eb[2]), __fmul_rn(2.0f, a2));
        const float s3 = __fsub_rn(__fadd_rn(A, eb[3]), __fmul_rn(2.0f, a3));
        if (s0 < best) { best = s0; bidx = cb + 0; }   // ascending order keeps
        if (s1 < best) { best = s1; bidx = cb + 1; }   // numpy first-index ties
        if (s2 < best) { best = s2; bidx = cb + 2; }
        if (s3 < best) { best = s3; bidx = cb + 3; }

        ebase += 4 * DIM;
        esqp  += 4;
    }

    // positive scores -> float bits order-preserving; low 32 = code (min code wins ties)
    const unsigned long long key =
        ((unsigned long long)__float_as_uint(best) << 32) | (unsigned long long)bidx;
    atomicMin(&keys[token], key);
}

// gather z_q, quantized = z + (z_q - z) exact; loss partials to 64 slots; counts.
__global__ __launch_bounds__(256) void vq_out(
    const float* __restrict__ z, const float* __restrict__ emb,
    const unsigned long long* __restrict__ keys, float* __restrict__ outq,
    double* __restrict__ lacc, int* __restrict__ counts)
{
    double ls = 0.0;
    for (int g = blockIdx.x * 256 + threadIdx.x; g < N_TOK * 32; g += 512 * 256) {
        const int t = g >> 5, dd = g & 31;
        const unsigned code = (unsigned)(keys[t] & 0xFFFFFFFFull);
        const float4 e4 = *(const float4*)(emb + ((size_t)code << 7) + (dd << 2));
        const float4 z4 = *(const float4*)(z + ((size_t)g << 2));

        const float dx = __fsub_rn(e4.x, z4.x);
        const float dy = __fsub_rn(e4.y, z4.y);
        const float dz = __fsub_rn(e4.z, z4.z);
        const float dw = __fsub_rn(e4.w, z4.w);

        float4 q;
        q.x = __fadd_rn(z4.x, dx);
        q.y = __fadd_rn(z4.y, dy);
        q.z = __fadd_rn(z4.z, dz);
        q.w = __fadd_rn(z4.w, dw);
        *(float4*)(outq + ((size_t)g << 2)) = q;

        ls += (double)__fmul_rn(dx, dx) + (double)__fmul_rn(dy, dy)
            + (double)__fmul_rn(dz, dz) + (double)__fmul_rn(dw, dw);
        if (dd == 0) atomicAdd(&counts[code], 1);
    }
#pragma unroll
    for (int off = 32; off > 0; off >>= 1) ls += __shfl_down(ls, off);
    __shared__ double wsum[4];
    if ((threadIdx.x & 63) == 0) wsum[threadIdx.x >> 6] = ls;
    __syncthreads();
    if (threadIdx.x == 0)
        atomicAdd(&lacc[blockIdx.x & 63], wsum[0] + wsum[1] + wsum[2] + wsum[3]);
}

__global__ __launch_bounds__(256) void vq_final(
    const int* __restrict__ counts, const double* __restrict__ lacc,
    float* __restrict__ outs)
{
    double h = 0.0;
    for (int k = threadIdx.x; k < KCODES; k += 256) {
        const double p = (double)counts[k] * (1.0 / (double)N_TOK);
        h += p * log(p + 1e-10);
    }
#pragma unroll
    for (int off = 32; off > 0; off >>= 1) h += __shfl_down(h, off);
    __shared__ double ws2[4];
    if ((threadIdx.x & 63) == 0) ws2[threadIdx.x >> 6] = h;
    __syncthreads();
    if (threadIdx.x == 0) {
        double L = 0.0;
        for (int i = 0; i < 64; ++i) L += lacc[i];
        outs[0] = (float)(1.25 * L / (double)((size_t)N_TOK * DIM));
        outs[1] = (float)exp(-(ws2[0] + ws2[1] + ws2[2] + ws2[3]));
    }
}

extern "C" void kernel_launch(void* const* d_in, const int* in_sizes, int n_in,
                              void* d_out, int out_size, void* d_ws, size_t ws_size,
                              hipStream_t stream) {
    const float* z   = (const float*)d_in[0];
    const float* emb = (const float*)d_in[1];

    float* outq = (float*)d_out;
    float* outs = outq + (size_t)N_TOK * DIM;

    char* ws = (char*)d_ws;
    unsigned long long* keys = (unsigned long long*)(ws);
    float*  esq    = (float*)(ws + 262144);
    int*    counts = (int*)(ws + 266240);
    double* lacc   = (double*)(ws + 270336);

    vq_prep<<<dim3(N_TOK / 256), dim3(256), 0, stream>>>(emb, esq, keys, counts, lacc);
    vq_argmin<<<dim3(SPLITS * (N_TOK / 256)), dim3(256), 0, stream>>>(z, emb, esq, keys);
    vq_out<<<dim3(512), dim3(256), 0, stream>>>(z, emb, keys, outq, lacc, counts);
    vq_final<<<dim3(1), dim3(256), 0, stream>>>(counts, lacc, outs);
}